// Round 13
// baseline (298.933 us; speedup 1.0000x reference)
//
#include <hip/hip_runtime.h>
#include <stdint.h>
#include <stddef.h>

#define M_DIM 2048
#define N_DIM 11008
#define K_DIM 4096
#define BM 128
#define BN 128
#define BKB 128            // K-bytes per tile (int8) == 128 int32 of W_q
#define NT (K_DIM / BKB)   // 32
#define NBM (M_DIM / BM)   // 16
#define NBN (N_DIM / BN)   // 86
#define GRID (NBM * NBN)   // 1376 (divisible by 8 -> XCD swizzle bijective)

typedef __attribute__((ext_vector_type(4))) int i4;
typedef __attribute__((ext_vector_type(4))) float f4;

#define VMCNT0() asm volatile("s_waitcnt vmcnt(0)" ::: "memory")
#define LGKM0() asm volatile("s_waitcnt lgkmcnt(0)" ::: "memory")
#define FENCE() asm volatile("" ::: "memory")
#define BARRIER()                 \
  do {                            \
    FENCE();                      \
    __builtin_amdgcn_s_barrier(); \
    FENCE();                      \
  } while (0)

__device__ inline void gload_lds16(const void* g, void* l) {
  __builtin_amdgcn_global_load_lds((const __attribute__((address_space(1))) void*)g,
                                   (__attribute__((address_space(3))) void*)l, 16, 0, 0);
}

// pack 4 int32 (range [-127,127]) low bytes -> 1 dword
__device__ inline int packlo(i4 v) {
  return (v[0] & 255) | ((v[1] & 255) << 8) | ((v[2] & 255) << 16) | (v[3] << 24);
}

// ---------------- x quantization ----------------

// x[row][4096] fp32 -> per-row int8 with scale xs[row] = rowmax/127 (symmetric RNE).
__global__ void __launch_bounds__(256) quant_x_kernel(const float* __restrict__ x,
                                                      signed char* __restrict__ xq,
                                                      float* __restrict__ xs) {
  __shared__ float red[256];
  const int row = blockIdx.x;
  const int tid = threadIdx.x;
  const f4* xr = (const f4*)(x + (size_t)row * K_DIM);  // 1024 f4 per row
  f4 v[4];
  float mx = 0.f;
#pragma unroll
  for (int j = 0; j < 4; ++j) {
    v[j] = xr[tid * 4 + j];
#pragma unroll
    for (int e = 0; e < 4; ++e) mx = fmaxf(mx, fabsf(v[j][e]));
  }
  red[tid] = mx;
  __syncthreads();
  for (int off = 128; off; off >>= 1) {
    if (tid < off) red[tid] = fmaxf(red[tid], red[tid + off]);
    __syncthreads();
  }
  const float rowmax = red[0];
  const float r = (rowmax > 0.f) ? 127.f / rowmax : 0.f;
  int p[4];
#pragma unroll
  for (int j = 0; j < 4; ++j) {
    int q[4];
#pragma unroll
    for (int e = 0; e < 4; ++e) {
      int qi = __float2int_rn(v[j][e] * r);
      qi = qi > 127 ? 127 : (qi < -127 ? -127 : qi);
      q[e] = qi;
    }
    p[j] = (q[0] & 255) | ((q[1] & 255) << 8) | ((q[2] & 255) << 16) | (q[3] << 24);
  }
  ((i4*)xq)[(size_t)row * 256 + tid] = i4{p[0], p[1], p[2], p[3]};
  if (tid == 0) xs[row] = (rowmax > 0.f) ? rowmax / 127.f : 1.f;
}

// ---- int8 GEMM, r10 frame + in-kernel W int32->int8 pack (cvt_w eliminated) ----
// 128x128 tile, BKB=128, 4 waves = 2 N-strips x 2 K-halves; wave-tile 128x64.
// A (xq int8): global_load_lds staging, unchanged from r10 (1-tile slack, vmcnt'd).
// B (W_q int32): reg-staged T14 split. Per thread, granule g=(tid&7)^(srow&7) of rows
// srow+{0,32,64,96}: 4x4 i4 int32 loads (8 rows x 128B coalesced per instr — NOT r12's
// scatter), packed to 16B via packlo, ds_write_b128 to slot i*4096+tid*16 — byte-
// identical layout/swizzle to r10's gload staging (read-side XOR unchanged).
// Tile t: [lgkm0; barrier: publish A(t)+B(t)] issue Bg1(t+1); reads a0-3,b; cluster1;
// vmcnt0 (retires g1); pack g1; issue A(t+1)+Bg2(t+1); reads a4-7; cluster2;
// vmcnt0 (retires A+g2); pack g2; 4x ds_write -> buf_other (its t-1 readers drained
// at this tile's top barrier -> race-free). VGPR peak ~232 <= 256 @ 2 blocks/CU.

#define STAGE_A(base, ko)                                                        \
  do {                                                                           \
    const int _ko = (ko);                                                        \
    gload_lds16(gA + _ko, (base) + wid * 1024);                                  \
    gload_lds16(gA + (size_t)32 * K_DIM + _ko, (base) + 4096 + wid * 1024);      \
    gload_lds16(gA + (size_t)64 * K_DIM + _ko, (base) + 8192 + wid * 1024);      \
    gload_lds16(gA + (size_t)96 * K_DIM + _ko, (base) + 12288 + wid * 1024);     \
  } while (0)

__global__ void __launch_bounds__(256, 2) gemm_i8(
    const signed char* __restrict__ Xq,   // [M, K] int8
    const int* __restrict__ Wq32,         // [N, K] int32 (raw input)
    const float* __restrict__ xs,         // [M] row scales
    const float* __restrict__ scale,      // [N]
    const float* __restrict__ bias,       // [N]
    float* __restrict__ out) {            // [M, N] fp32
  __shared__ __align__(16) char lds[65536];  // 2 x 32KB {A@0,B@16K}; epilogue reuses 64KB

  const int tid = threadIdx.x;
  const int lane = tid & 63;
  const int wid = tid >> 6;   // 0..3
  const int s = wid & 1;      // N-strip (64 cols)
  const int h = wid >> 1;     // K-half (64 bytes of 128)
  const int fr = lane & 15;
  const int fq = lane >> 4;

  // T1: XCD-aware swizzle (1376 % 8 == 0 -> bijective). Consecutive wg share bn.
  const int bid = blockIdx.x;
  const int wg = (bid & 7) * (GRID / 8) + (bid >> 3);
  const int bm = wg & 15;
  const int bn = wg >> 4;

  // A staging source (inverse-swizzled): row = tid>>3 (+32 chunks), granule=(tid&7)^(row&7)
  const int srow = tid >> 3;
  const int g = (tid & 7) ^ (srow & 7);
  const signed char* gA = Xq + (size_t)(bm * BM + srow) * K_DIM + g * 16;

  // B staging source: same granule of W_q int32 rows bn*128 + srow + {0,32,64,96};
  // granule g covers ints g*16..g*16+16 (64B) of the 128-int K-tile.
  const int* gW = Wq32 + (size_t)(bn * BN + srow) * K_DIM + g * 16;

  // ds_read: byte col = (h*64 + fq*16) ^ ((row&7)<<4); row&7 == lane&7 for all frags
  const int cb = ((h * 64) + (fq * 16)) ^ ((lane & 7) << 4);

  char* const buf0 = lds;
  char* const buf1 = lds + 32768;

  // ---- prologue: stage tile 0 (A gload; B reg->pack->LDS)
  STAGE_A(buf0, 0);
  {
    i4 u[16];
#pragma unroll
    for (int i = 0; i < 4; ++i)
#pragma unroll
      for (int q = 0; q < 4; ++q)
        u[i * 4 + q] = *(const i4*)(gW + (size_t)i * 32 * K_DIM + q * 4);
    VMCNT0();
#pragma unroll
    for (int i = 0; i < 4; ++i) {
      i4 p = i4{packlo(u[i * 4]), packlo(u[i * 4 + 1]),
                packlo(u[i * 4 + 2]), packlo(u[i * 4 + 3])};
      *(i4*)(buf0 + 16384 + i * 4096 + tid * 16) = p;
    }
  }

  i4 acc[8][4] = {};

#pragma unroll 1
  for (int t = 0; t < NT; ++t) {
    char* const bc = (t & 1) ? buf1 : buf0;
    char* const bo = (t & 1) ? buf0 : buf1;
    const bool more = (t + 1 < NT);
    const int tk = (t + 1) * BKB;  // int32 index == byte index

    LGKM0();     // my ds_writes (B(t)) + reads drained before barrier
    BARRIER();   // publish A(t) (vmcnt'd end of t-1) + B(t) (ds_write, lgkm'd)

    // issue B group1 (rows srow, srow+32) for t+1
    i4 u[8];
    if (more) {
#pragma unroll
      for (int i = 0; i < 2; ++i)
#pragma unroll
        for (int q = 0; q < 4; ++q)
          u[i * 4 + q] = *(const i4*)(gW + (size_t)i * 32 * K_DIM + tk + q * 4);
    }

    i4 a0[4], b[4], a1[4];
#pragma unroll
    for (int m = 0; m < 4; ++m)
      a0[m] = *(const i4*)(bc + (m * 16 + fr) * 128 + cb);
#pragma unroll
    for (int j = 0; j < 4; ++j)
      b[j] = *(const i4*)(bc + 16384 + (s * 64 + j * 16 + fr) * 128 + cb);
    __builtin_amdgcn_s_setprio(1);
#pragma unroll
    for (int m = 0; m < 4; ++m)
#pragma unroll
      for (int j = 0; j < 4; ++j)
        acc[m][j] = __builtin_amdgcn_mfma_i32_16x16x64_i8(a0[m], b[j], acc[m][j], 0, 0, 0);
    __builtin_amdgcn_s_setprio(0);

    VMCNT0();  // retire g1 (issued pre-cluster1; ~cluster of slack + co-block overlap)
    i4 p0, p1, p2, p3;
    if (more) {
      p0 = i4{packlo(u[0]), packlo(u[1]), packlo(u[2]), packlo(u[3])};
      p1 = i4{packlo(u[4]), packlo(u[5]), packlo(u[6]), packlo(u[7])};
      STAGE_A(bo, tk);  // A(t+1) gloads
#pragma unroll
      for (int i = 0; i < 2; ++i)  // B group2 (rows srow+64, srow+96)
#pragma unroll
        for (int q = 0; q < 4; ++q)
          u[i * 4 + q] = *(const i4*)(gW + (size_t)(i + 2) * 32 * K_DIM + tk + q * 4);
    }

#pragma unroll
    for (int m = 0; m < 4; ++m)
      a1[m] = *(const i4*)(bc + ((m + 4) * 16 + fr) * 128 + cb);
    __builtin_amdgcn_s_setprio(1);
#pragma unroll
    for (int m = 0; m < 4; ++m)
#pragma unroll
      for (int j = 0; j < 4; ++j)
        acc[m + 4][j] = __builtin_amdgcn_mfma_i32_16x16x64_i8(a1[m], b[j], acc[m + 4][j], 0, 0, 0);
    __builtin_amdgcn_s_setprio(0);

    VMCNT0();  // retire A(t+1) gloads + g2
    if (more) {
      p2 = i4{packlo(u[0]), packlo(u[1]), packlo(u[2]), packlo(u[3])};
      p3 = i4{packlo(u[4]), packlo(u[5]), packlo(u[6]), packlo(u[7])};
      *(i4*)(bo + 16384 + 0 * 4096 + tid * 16) = p0;
      *(i4*)(bo + 16384 + 1 * 4096 + tid * 16) = p1;
      *(i4*)(bo + 16384 + 2 * 4096 + tid * 16) = p2;
      *(i4*)(bo + 16384 + 3 * 4096 + tid * 16) = p3;
    }
  }

  // ---- epilogue: reduce K-half pairs via LDS (i32, fq-XOR swizzle -> 2-way, free),
  // then dequant + bias + store. C/D frag: col=j*16+fr, row=m*16+fq*4+jj.
  LGKM0();
  BARRIER();
  if (h == 1) {
    int* red = (int*)(lds + s * 32768);  // [128][64] i32 per strip
#pragma unroll
    for (int m = 0; m < 8; ++m)
#pragma unroll
      for (int j = 0; j < 4; ++j)
#pragma unroll
        for (int jj = 0; jj < 4; ++jj)
          red[(m * 16 + fq * 4 + jj) * 64 + ((j * 16 + fr) ^ (fq << 4))] = acc[m][j][jj];
  }
  BARRIER();
  if (h == 0) {
    const int* red = (const int*)(lds + s * 32768);
#pragma unroll
    for (int j = 0; j < 4; ++j) {
      const int c = bn * BN + s * 64 + j * 16 + fr;
      const float sc = scale[c];
      const float bi = bias[c];
#pragma unroll
      for (int m = 0; m < 8; ++m) {
        const int r0 = bm * BM + m * 16 + fq * 4;
#pragma unroll
        for (int jj = 0; jj < 4; ++jj) {
          const int sum = acc[m][j][jj] +
                          red[(m * 16 + fq * 4 + jj) * 64 + ((j * 16 + fr) ^ (fq << 4))];
          out[(size_t)(r0 + jj) * N_DIM + c] = (float)sum * xs[r0 + jj] * sc + bi;
        }
      }
    }
  }
}

// ---------------- fallback (only if d_ws too small) ----------------

__global__ void __launch_bounds__(256) naive_kernel(
    const float* __restrict__ x, const int* __restrict__ w,
    const float* __restrict__ scale, const float* __restrict__ bias,
    float* __restrict__ out) {
  size_t idx = (size_t)blockIdx.x * 256 + threadIdx.x;
  if (idx >= (size_t)M_DIM * N_DIM) return;
  int m = (int)(idx / N_DIM);
  int n = (int)(idx % N_DIM);
  const float* xr = x + (size_t)m * K_DIM;
  const int* wr = w + (size_t)n * K_DIM;
  float acc = 0.f;
  for (int k = 0; k < K_DIM; k += 4) {
    f4 xv = *(const f4*)(xr + k);
    i4 wv = *(const i4*)(wr + k);
    acc += xv[0] * (float)wv[0];
    acc += xv[1] * (float)wv[1];
    acc += xv[2] * (float)wv[2];
    acc += xv[3] * (float)wv[3];
  }
  out[idx] = acc * scale[n] + bias[n];
}

// ---------------- launch ----------------

extern "C" void kernel_launch(void* const* d_in, const int* in_sizes, int n_in,
                              void* d_out, int out_size, void* d_ws, size_t ws_size,
                              hipStream_t stream) {
  const float* x = (const float*)d_in[0];
  const int* wq = (const int*)d_in[1];
  const float* scale = (const float*)d_in[2];
  const float* bias = (const float*)d_in[3];
  float* out = (float*)d_out;

  const size_t xq_bytes = (size_t)M_DIM * K_DIM;         // 8.4 MB
  const size_t xs_bytes = (size_t)M_DIM * sizeof(float); // 8 KB

  if (ws_size >= xq_bytes + xs_bytes) {
    signed char* xq = (signed char*)d_ws;
    float* xs = (float*)((char*)d_ws + xq_bytes);

    quant_x_kernel<<<M_DIM, 256, 0, stream>>>(x, xq, xs);
    gemm_i8<<<GRID, 256, 0, stream>>>(xq, wq, xs, scale, bias, out);
  } else {
    const size_t total = (size_t)M_DIM * N_DIM;
    naive_kernel<<<(unsigned)((total + 255) / 256), 256, 0, stream>>>(x, wq, scale, bias, out);
  }
}

// Round 14
// 161.756 us; speedup vs baseline: 1.8481x; 1.8481x over previous
//
#include <hip/hip_runtime.h>
#include <stdint.h>
#include <stddef.h>

#define M_DIM 2048
#define N_DIM 11008
#define K_DIM 4096
#define BM 128
#define BN 128
#define BKB 128            // K-bytes per tile (int8) -> 128B rows, conflict-free XOR geometry
#define NT (K_DIM / BKB)   // 32
#define NBM (M_DIM / BM)   // 16
#define NBN (N_DIM / BN)   // 86
#define GRID (NBM * NBN)   // 1376 (divisible by 8 -> XCD swizzle bijective)

typedef __attribute__((ext_vector_type(4))) int i4;
typedef __attribute__((ext_vector_type(4))) float f4;

#define VMCNT0() asm volatile("s_waitcnt vmcnt(0)" ::: "memory")
#define FENCE() asm volatile("" ::: "memory")
#define BARRIER()                 \
  do {                            \
    FENCE();                      \
    __builtin_amdgcn_s_barrier(); \
    FENCE();                      \
  } while (0)

__device__ inline void gload_lds16(const void* g, void* l) {
  __builtin_amdgcn_global_load_lds((const __attribute__((address_space(1))) void*)g,
                                   (__attribute__((address_space(3))) void*)l, 16, 0, 0);
}

// ---------------- conversion kernels ----------------

// x[row][4096] fp32 -> per-row int8 with scale xs[row] = rowmax/127 (symmetric RNE).
__global__ void __launch_bounds__(256) quant_x_kernel(const float* __restrict__ x,
                                                      signed char* __restrict__ xq,
                                                      float* __restrict__ xs) {
  __shared__ float red[256];
  const int row = blockIdx.x;
  const int tid = threadIdx.x;
  const f4* xr = (const f4*)(x + (size_t)row * K_DIM);  // 1024 f4 per row
  f4 v[4];
  float mx = 0.f;
#pragma unroll
  for (int j = 0; j < 4; ++j) {
    v[j] = xr[tid * 4 + j];
#pragma unroll
    for (int e = 0; e < 4; ++e) mx = fmaxf(mx, fabsf(v[j][e]));
  }
  red[tid] = mx;
  __syncthreads();
  for (int off = 128; off; off >>= 1) {
    if (tid < off) red[tid] = fmaxf(red[tid], red[tid + off]);
    __syncthreads();
  }
  const float rowmax = red[0];
  const float r = (rowmax > 0.f) ? 127.f / rowmax : 0.f;
  int p[4];
#pragma unroll
  for (int j = 0; j < 4; ++j) {
    int q[4];
#pragma unroll
    for (int e = 0; e < 4; ++e) {
      int qi = __float2int_rn(v[j][e] * r);
      qi = qi > 127 ? 127 : (qi < -127 ? -127 : qi);
      q[e] = qi;
    }
    p[j] = (q[0] & 255) | ((q[1] & 255) << 8) | ((q[2] & 255) << 16) | (q[3] << 24);
  }
  ((i4*)xq)[(size_t)row * 256 + tid] = i4{p[0], p[1], p[2], p[3]};
  if (tid == 0) xs[row] = (rowmax > 0.f) ? rowmax / 127.f : 1.f;
}

// W_q arrives as int32 per element (range [-127,127]); pack low bytes -> int8.
// BW-floor kernel: 180MB read + 45MB write ~= 36us. Fusing this into the gemm was
// tried (r13) and regressed 2x: the pack's load->use gap is <= 1 MFMA cluster at
// the register budget -> raw HBM latency twice per tile. Keep it standalone.
__global__ void __launch_bounds__(256) cvt_w_kernel(const int* __restrict__ w,
                                                    i4* __restrict__ wq8, int n16) {
  int i = blockIdx.x * 256 + threadIdx.x;
  if (i >= n16) return;
  const i4* src = (const i4*)w + 4 * (size_t)i;
  i4 v0 = src[0], v1 = src[1], v2 = src[2], v3 = src[3];
  i4 o;
  o[0] = (v0[0] & 255) | ((v0[1] & 255) << 8) | ((v0[2] & 255) << 16) | (v0[3] << 24);
  o[1] = (v1[0] & 255) | ((v1[1] & 255) << 8) | ((v1[2] & 255) << 16) | (v1[3] << 24);
  o[2] = (v2[0] & 255) | ((v2[1] & 255) << 8) | ((v2[2] & 255) << 16) | (v2[3] << 24);
  o[3] = (v3[0] & 255) | ((v3[1] & 255) << 8) | ((v3[2] & 255) << 16) | (v3[3] << 24);
  wq8[i] = o;
}

// ------- int8 GEMM (r10, best measured: 121us): 128x128 tile, BKB=128, 4 waves -------
// 4 waves = 2 N-strips (64 cols) x 2 K-halves (64 bytes of 128); wave-tile 128x64.
// Per wave per tile: 12 ds_read_b128 (a 8, b 4) + 32 x mfma_i32_16x16x64_i8.
// LDS: 2 bufs x 32KB {A[128][128B]@0, B[128][128B]@16K}; 128B rows + XOR swizzle
// byte^=(row&7)<<4 both sides -> 0 bank conflicts (verified r3-r12).
// Iter t: vmcnt(0) [counted-equivalent: only S(t)'s 8 loads outstanding, issued t-1,
// ~1 full tile of slack >= HBM latency]; barrier; STAGE8(t+1) -> other buf; reads;
// 2 MFMA clusters under setprio. Co-resident 2nd block fills the opposite pipe.
// Epilogue: K-half i32 reduce via LDS (fq-XOR, 2-way=free), dequant xs*scale+bias.
// Local-optimum notes: BM=64 (r11) -> FETCH x1.75, slower; B-direct-to-reg (r12) ->
// VMEM scatter, slower; fused W-pack (r13) -> latency-exposed, 2x slower.

#define STAGE8(base, gA, gB, ko)                                                 \
  do {                                                                           \
    const int _ko = (ko);                                                        \
    gload_lds16((gA) + _ko, (base) + wid * 1024);                                \
    gload_lds16((gA) + (size_t)32 * K_DIM + _ko, (base) + 4096 + wid * 1024);    \
    gload_lds16((gA) + (size_t)64 * K_DIM + _ko, (base) + 8192 + wid * 1024);    \
    gload_lds16((gA) + (size_t)96 * K_DIM + _ko, (base) + 12288 + wid * 1024);   \
    gload_lds16((gB) + _ko, (base) + 16384 + wid * 1024);                        \
    gload_lds16((gB) + (size_t)32 * K_DIM + _ko, (base) + 20480 + wid * 1024);   \
    gload_lds16((gB) + (size_t)64 * K_DIM + _ko, (base) + 24576 + wid * 1024);   \
    gload_lds16((gB) + (size_t)96 * K_DIM + _ko, (base) + 28672 + wid * 1024);   \
  } while (0)

__global__ void __launch_bounds__(256, 2) gemm_i8(
    const signed char* __restrict__ Xq,   // [M, K] int8
    const signed char* __restrict__ Wq,   // [N, K] int8
    const float* __restrict__ xs,         // [M] row scales
    const float* __restrict__ scale,      // [N]
    const float* __restrict__ bias,       // [N]
    float* __restrict__ out) {            // [M, N] fp32
  __shared__ __align__(16) char lds[65536];  // 2 x 32KB; epilogue reuses 64KB

  const int tid = threadIdx.x;
  const int lane = tid & 63;
  const int wid = tid >> 6;   // 0..3
  const int s = wid & 1;      // N-strip (64 cols)
  const int h = wid >> 1;     // K-half (64 bytes of 128)
  const int fr = lane & 15;
  const int fq = lane >> 4;

  // T1: XCD-aware swizzle (1376 % 8 == 0 -> bijective). Consecutive wg share bn.
  const int bid = blockIdx.x;
  const int wg = (bid & 7) * (GRID / 8) + (bid >> 3);
  const int bm = wg & 15;
  const int bn = wg >> 4;

  // staging source (inverse-swizzled): row = tid>>3 (+32*i), granule = (tid&7)^(row&7)
  const int srow = tid >> 3;
  const int scol = ((tid & 7) ^ (srow & 7)) * 16;  // bytes
  const signed char* gA = Xq + (size_t)(bm * BM + srow) * K_DIM + scol;
  const signed char* gB = Wq + (size_t)(bn * BN + srow) * K_DIM + scol;

  // ds_read: byte col = (h*64 + fq*16) ^ ((row&7)<<4); row&7 == lane&7 for all frags
  const int cb = ((h * 64) + (fq * 16)) ^ ((lane & 7) << 4);

  char* const buf0 = lds;
  char* const buf1 = lds + 32768;

  STAGE8(buf0, gA, gB, 0);

  i4 acc[8][4] = {};

#pragma unroll 1
  for (int t = 0; t < NT; ++t) {
    char* const bc = (t & 1) ? buf1 : buf0;
    char* const bo = (t & 1) ? buf0 : buf1;
    VMCNT0();    // S(t) complete (issued iter t-1; ~1 full tile of slack)
    BARRIER();   // publish bc; prior readers of bo drained pre-barrier
    if (t + 1 < NT) STAGE8(bo, gA, gB, (t + 1) * BKB);

    i4 a[8], b[4];
#pragma unroll
    for (int m = 0; m < 8; ++m)
      a[m] = *(const i4*)(bc + (m * 16 + fr) * 128 + cb);
#pragma unroll
    for (int j = 0; j < 4; ++j)
      b[j] = *(const i4*)(bc + 16384 + (s * 64 + j * 16 + fr) * 128 + cb);
    __builtin_amdgcn_s_setprio(1);
#pragma unroll
    for (int m = 0; m < 4; ++m)
#pragma unroll
      for (int j = 0; j < 4; ++j)
        acc[m][j] = __builtin_amdgcn_mfma_i32_16x16x64_i8(a[m], b[j], acc[m][j], 0, 0, 0);
    __builtin_amdgcn_s_setprio(0);
    __builtin_amdgcn_s_setprio(1);
#pragma unroll
    for (int m = 4; m < 8; ++m)
#pragma unroll
      for (int j = 0; j < 4; ++j)
        acc[m][j] = __builtin_amdgcn_mfma_i32_16x16x64_i8(a[m], b[j], acc[m][j], 0, 0, 0);
    __builtin_amdgcn_s_setprio(0);
  }

  // ---- epilogue: reduce K-half pairs via LDS (i32, fq-XOR swizzle -> 2-way, free),
  // then dequant + bias + store. C/D frag: col=j*16+fr, row=m*16+fq*4+jj.
  BARRIER();
  if (h == 1) {
    int* red = (int*)(lds + s * 32768);  // [128][64] i32 per strip
#pragma unroll
    for (int m = 0; m < 8; ++m)
#pragma unroll
      for (int j = 0; j < 4; ++j)
#pragma unroll
        for (int jj = 0; jj < 4; ++jj)
          red[(m * 16 + fq * 4 + jj) * 64 + ((j * 16 + fr) ^ (fq << 4))] = acc[m][j][jj];
  }
  BARRIER();
  if (h == 0) {
    const int* red = (const int*)(lds + s * 32768);
#pragma unroll
    for (int j = 0; j < 4; ++j) {
      const int c = bn * BN + s * 64 + j * 16 + fr;
      const float sc = scale[c];
      const float bi = bias[c];
#pragma unroll
      for (int m = 0; m < 8; ++m) {
        const int r0 = bm * BM + m * 16 + fq * 4;
#pragma unroll
        for (int jj = 0; jj < 4; ++jj) {
          const int sum = acc[m][j][jj] +
                          red[(m * 16 + fq * 4 + jj) * 64 + ((j * 16 + fr) ^ (fq << 4))];
          out[(size_t)(r0 + jj) * N_DIM + c] = (float)sum * xs[r0 + jj] * sc + bi;
        }
      }
    }
  }
}

// ---------------- fallback (only if d_ws too small) ----------------

__global__ void __launch_bounds__(256) naive_kernel(
    const float* __restrict__ x, const int* __restrict__ w,
    const float* __restrict__ scale, const float* __restrict__ bias,
    float* __restrict__ out) {
  size_t idx = (size_t)blockIdx.x * 256 + threadIdx.x;
  if (idx >= (size_t)M_DIM * N_DIM) return;
  int m = (int)(idx / N_DIM);
  int n = (int)(idx % N_DIM);
  const float* xr = x + (size_t)m * K_DIM;
  const int* wr = w + (size_t)n * K_DIM;
  float acc = 0.f;
  for (int k = 0; k < K_DIM; k += 4) {
    f4 xv = *(const f4*)(xr + k);
    i4 wv = *(const i4*)(wr + k);
    acc += xv[0] * (float)wv[0];
    acc += xv[1] * (float)wv[1];
    acc += xv[2] * (float)wv[2];
    acc += xv[3] * (float)wv[3];
  }
  out[idx] = acc * scale[n] + bias[n];
}

// ---------------- launch ----------------

extern "C" void kernel_launch(void* const* d_in, const int* in_sizes, int n_in,
                              void* d_out, int out_size, void* d_ws, size_t ws_size,
                              hipStream_t stream) {
  const float* x = (const float*)d_in[0];
  const int* wq = (const int*)d_in[1];
  const float* scale = (const float*)d_in[2];
  const float* bias = (const float*)d_in[3];
  float* out = (float*)d_out;

  const size_t xq_bytes = (size_t)M_DIM * K_DIM;         // 8.4 MB
  const size_t xs_bytes = (size_t)M_DIM * sizeof(float); // 8 KB
  const size_t wq_bytes = (size_t)N_DIM * K_DIM;         // 45.1 MB

  if (ws_size >= xq_bytes + xs_bytes + wq_bytes) {
    signed char* xq = (signed char*)d_ws;
    float* xs = (float*)((char*)d_ws + xq_bytes);
    signed char* wq8 = (signed char*)((char*)d_ws + xq_bytes + xs_bytes);

    quant_x_kernel<<<M_DIM, 256, 0, stream>>>(x, xq, xs);

    const int n16 = N_DIM * K_DIM / 16;
    cvt_w_kernel<<<(n16 + 255) / 256, 256, 0, stream>>>(wq, (i4*)wq8, n16);

    gemm_i8<<<GRID, 256, 0, stream>>>(xq, wq8, xs, scale, bias, out);
  } else {
    const size_t total = (size_t)M_DIM * N_DIM;
    naive_kernel<<<(unsigned)((total + 255) / 256), 256, 0, stream>>>(x, wq, scale, bias, out);
  }
}

// Round 15
// 159.670 us; speedup vs baseline: 1.8722x; 1.0131x over previous
//
#include <hip/hip_runtime.h>
#include <stdint.h>
#include <stddef.h>

#define M_DIM 2048
#define N_DIM 11008
#define K_DIM 4096
#define BM 128
#define BN 128
#define BKB 128            // K-bytes per tile (int8) -> 128B rows, conflict-free XOR geometry
#define NT (K_DIM / BKB)   // 32
#define NBM (M_DIM / BM)   // 16
#define NBN (N_DIM / BN)   // 86
#define GRID (NBM * NBN)   // 1376 (divisible by 8 -> XCD swizzle bijective)
#define NW16 (N_DIM * K_DIM / 16)  // 2,818,048 = 11008 * 256 exactly

typedef __attribute__((ext_vector_type(4))) int i4;
typedef __attribute__((ext_vector_type(4))) float f4;

#define VMCNT0() asm volatile("s_waitcnt vmcnt(0)" ::: "memory")
#define FENCE() asm volatile("" ::: "memory")
#define BARRIER()                 \
  do {                            \
    FENCE();                      \
    __builtin_amdgcn_s_barrier(); \
    FENCE();                      \
  } while (0)

__device__ inline void gload_lds16(const void* g, void* l) {
  __builtin_amdgcn_global_load_lds((const __attribute__((address_space(1))) void*)g,
                                   (__attribute__((address_space(3))) void*)l, 16, 0, 0);
}

// ---------------- fused prep: x row-quant + W int32->int8 pack ----------------
// Both sub-tasks are BW-floor; fusing removes one launch boundary and overlaps the
// quant blocks' reduce latency with the pack blocks' streaming. Combined traffic
// 267 MB ~= 42us floor. Blocks [0,2048): quantize x row; [2048,13056): pack W.

__global__ void __launch_bounds__(256) prep_kernel(
    const float* __restrict__ x, signed char* __restrict__ xq, float* __restrict__ xs,
    const int* __restrict__ w, i4* __restrict__ wq8) {
  __shared__ float red[256];
  const int bid = blockIdx.x;
  const int tid = threadIdx.x;

  if (bid < M_DIM) {
    // ---- x[row][4096] fp32 -> int8, scale xs[row] = rowmax/127 (symmetric RNE)
    const int row = bid;
    const f4* xr = (const f4*)(x + (size_t)row * K_DIM);  // 1024 f4 per row
    f4 v[4];
    float mx = 0.f;
#pragma unroll
    for (int j = 0; j < 4; ++j) {
      v[j] = xr[tid * 4 + j];
#pragma unroll
      for (int e = 0; e < 4; ++e) mx = fmaxf(mx, fabsf(v[j][e]));
    }
    red[tid] = mx;
    __syncthreads();
    for (int off = 128; off; off >>= 1) {
      if (tid < off) red[tid] = fmaxf(red[tid], red[tid + off]);
      __syncthreads();
    }
    const float rowmax = red[0];
    const float r = (rowmax > 0.f) ? 127.f / rowmax : 0.f;
    int p[4];
#pragma unroll
    for (int j = 0; j < 4; ++j) {
      int q[4];
#pragma unroll
      for (int e = 0; e < 4; ++e) {
        int qi = __float2int_rn(v[j][e] * r);
        qi = qi > 127 ? 127 : (qi < -127 ? -127 : qi);
        q[e] = qi;
      }
      p[j] = (q[0] & 255) | ((q[1] & 255) << 8) | ((q[2] & 255) << 16) | (q[3] << 24);
    }
    ((i4*)xq)[(size_t)row * 256 + tid] = i4{p[0], p[1], p[2], p[3]};
    if (tid == 0) xs[row] = (rowmax > 0.f) ? rowmax / 127.f : 1.f;
  } else {
    // ---- W_q int32 (range [-127,127]) -> int8: pack low bytes, 16 ints/thread.
    // Grid sized exactly: (13056-2048)*256 == NW16, no bounds check needed.
    const size_t i = (size_t)(bid - M_DIM) * 256 + tid;
    const i4* src = (const i4*)w + 4 * i;
    i4 v0 = src[0], v1 = src[1], v2 = src[2], v3 = src[3];
    i4 o;
    o[0] = (v0[0] & 255) | ((v0[1] & 255) << 8) | ((v0[2] & 255) << 16) | (v0[3] << 24);
    o[1] = (v1[0] & 255) | ((v1[1] & 255) << 8) | ((v1[2] & 255) << 16) | (v1[3] << 24);
    o[2] = (v2[0] & 255) | ((v2[1] & 255) << 8) | ((v2[2] & 255) << 16) | (v2[3] << 24);
    o[3] = (v3[0] & 255) | ((v3[1] & 255) << 8) | ((v3[2] & 255) << 16) | (v3[3] << 24);
    wq8[i] = o;
  }
}

// ------- int8 GEMM (r10/r14, best measured: ~114us): 128x128 tile, BKB=128, 4 waves ----
// 4 waves = 2 N-strips (64 cols) x 2 K-halves (64 bytes of 128); wave-tile 128x64.
// Per wave per tile: 12 ds_read_b128 (a 8, b 4) + 32 x mfma_i32_16x16x64_i8.
// LDS: 2 bufs x 32KB {A[128][128B]@0, B[128][128B]@16K}; 128B rows + XOR swizzle
// byte^=(row&7)<<4 both sides -> 0 bank conflicts (verified r3-r14).
// Iter t: vmcnt(0) [counted-equivalent: only S(t)'s 8 loads outstanding, issued t-1,
// ~1 full tile of slack >= HBM latency]; barrier; STAGE8(t+1) -> other buf; reads;
// 2 MFMA clusters under setprio. Co-resident 2nd block fills the opposite pipe.
// Epilogue: K-half i32 reduce via LDS (fq-XOR, 2-way=free), dequant xs*scale+bias.
// Local-optimum map: BK=32 3-block (r9) -> 4-way conflicts + L2 thrash; BM=64 (r11)
// -> FETCH x1.75; B-direct-to-reg (r12) -> VMEM scatter; fused W-pack (r13) ->
// latency-exposed (load->use gap <= 1 cluster at this reg budget), 2x slower.
// Deeper pipelining (8-phase 256^2) blocked by tail: 344 blocks @ 1 block/CU -> ~25% loss.

#define STAGE8(base, gA, gB, ko)                                                 \
  do {                                                                           \
    const int _ko = (ko);                                                        \
    gload_lds16((gA) + _ko, (base) + wid * 1024);                                \
    gload_lds16((gA) + (size_t)32 * K_DIM + _ko, (base) + 4096 + wid * 1024);    \
    gload_lds16((gA) + (size_t)64 * K_DIM + _ko, (base) + 8192 + wid * 1024);    \
    gload_lds16((gA) + (size_t)96 * K_DIM + _ko, (base) + 12288 + wid * 1024);   \
    gload_lds16((gB) + _ko, (base) + 16384 + wid * 1024);                        \
    gload_lds16((gB) + (size_t)32 * K_DIM + _ko, (base) + 20480 + wid * 1024);   \
    gload_lds16((gB) + (size_t)64 * K_DIM + _ko, (base) + 24576 + wid * 1024);   \
    gload_lds16((gB) + (size_t)96 * K_DIM + _ko, (base) + 28672 + wid * 1024);   \
  } while (0)

__global__ void __launch_bounds__(256, 2) gemm_i8(
    const signed char* __restrict__ Xq,   // [M, K] int8
    const signed char* __restrict__ Wq,   // [N, K] int8
    const float* __restrict__ xs,         // [M] row scales
    const float* __restrict__ scale,      // [N]
    const float* __restrict__ bias,       // [N]
    float* __restrict__ out) {            // [M, N] fp32
  __shared__ __align__(16) char lds[65536];  // 2 x 32KB; epilogue reuses 64KB

  const int tid = threadIdx.x;
  const int lane = tid & 63;
  const int wid = tid >> 6;   // 0..3
  const int s = wid & 1;      // N-strip (64 cols)
  const int h = wid >> 1;     // K-half (64 bytes of 128)
  const int fr = lane & 15;
  const int fq = lane >> 4;

  // T1: XCD-aware swizzle (1376 % 8 == 0 -> bijective). Consecutive wg share bn.
  const int bid = blockIdx.x;
  const int wg = (bid & 7) * (GRID / 8) + (bid >> 3);
  const int bm = wg & 15;
  const int bn = wg >> 4;

  // staging source (inverse-swizzled): row = tid>>3 (+32*i), granule = (tid&7)^(row&7)
  const int srow = tid >> 3;
  const int scol = ((tid & 7) ^ (srow & 7)) * 16;  // bytes
  const signed char* gA = Xq + (size_t)(bm * BM + srow) * K_DIM + scol;
  const signed char* gB = Wq + (size_t)(bn * BN + srow) * K_DIM + scol;

  // ds_read: byte col = (h*64 + fq*16) ^ ((row&7)<<4); row&7 == lane&7 for all frags
  const int cb = ((h * 64) + (fq * 16)) ^ ((lane & 7) << 4);

  char* const buf0 = lds;
  char* const buf1 = lds + 32768;

  STAGE8(buf0, gA, gB, 0);

  i4 acc[8][4] = {};

#pragma unroll 1
  for (int t = 0; t < NT; ++t) {
    char* const bc = (t & 1) ? buf1 : buf0;
    char* const bo = (t & 1) ? buf0 : buf1;
    VMCNT0();    // S(t) complete (issued iter t-1; ~1 full tile of slack)
    BARRIER();   // publish bc; prior readers of bo drained pre-barrier
    if (t + 1 < NT) STAGE8(bo, gA, gB, (t + 1) * BKB);

    i4 a[8], b[4];
#pragma unroll
    for (int m = 0; m < 8; ++m)
      a[m] = *(const i4*)(bc + (m * 16 + fr) * 128 + cb);
#pragma unroll
    for (int j = 0; j < 4; ++j)
      b[j] = *(const i4*)(bc + 16384 + (s * 64 + j * 16 + fr) * 128 + cb);
    __builtin_amdgcn_s_setprio(1);
#pragma unroll
    for (int m = 0; m < 4; ++m)
#pragma unroll
      for (int j = 0; j < 4; ++j)
        acc[m][j] = __builtin_amdgcn_mfma_i32_16x16x64_i8(a[m], b[j], acc[m][j], 0, 0, 0);
    __builtin_amdgcn_s_setprio(0);
    __builtin_amdgcn_s_setprio(1);
#pragma unroll
    for (int m = 4; m < 8; ++m)
#pragma unroll
      for (int j = 0; j < 4; ++j)
        acc[m][j] = __builtin_amdgcn_mfma_i32_16x16x64_i8(a[m], b[j], acc[m][j], 0, 0, 0);
    __builtin_amdgcn_s_setprio(0);
  }

  // ---- epilogue: reduce K-half pairs via LDS (i32, fq-XOR swizzle -> 2-way, free),
  // then dequant + bias + store. C/D frag: col=j*16+fr, row=m*16+fq*4+jj.
  BARRIER();
  if (h == 1) {
    int* red = (int*)(lds + s * 32768);  // [128][64] i32 per strip
#pragma unroll
    for (int m = 0; m < 8; ++m)
#pragma unroll
      for (int j = 0; j < 4; ++j)
#pragma unroll
        for (int jj = 0; jj < 4; ++jj)
          red[(m * 16 + fq * 4 + jj) * 64 + ((j * 16 + fr) ^ (fq << 4))] = acc[m][j][jj];
  }
  BARRIER();
  if (h == 0) {
    const int* red = (const int*)(lds + s * 32768);
#pragma unroll
    for (int j = 0; j < 4; ++j) {
      const int c = bn * BN + s * 64 + j * 16 + fr;
      const float sc = scale[c];
      const float bi = bias[c];
#pragma unroll
      for (int m = 0; m < 8; ++m) {
        const int r0 = bm * BM + m * 16 + fq * 4;
#pragma unroll
        for (int jj = 0; jj < 4; ++jj) {
          const int sum = acc[m][j][jj] +
                          red[(m * 16 + fq * 4 + jj) * 64 + ((j * 16 + fr) ^ (fq << 4))];
          out[(size_t)(r0 + jj) * N_DIM + c] = (float)sum * xs[r0 + jj] * sc + bi;
        }
      }
    }
  }
}

// ---------------- fallback (only if d_ws too small) ----------------

__global__ void __launch_bounds__(256) naive_kernel(
    const float* __restrict__ x, const int* __restrict__ w,
    const float* __restrict__ scale, const float* __restrict__ bias,
    float* __restrict__ out) {
  size_t idx = (size_t)blockIdx.x * 256 + threadIdx.x;
  if (idx >= (size_t)M_DIM * N_DIM) return;
  int m = (int)(idx / N_DIM);
  int n = (int)(idx % N_DIM);
  const float* xr = x + (size_t)m * K_DIM;
  const int* wr = w + (size_t)n * K_DIM;
  float acc = 0.f;
  for (int k = 0; k < K_DIM; k += 4) {
    f4 xv = *(const f4*)(xr + k);
    i4 wv = *(const i4*)(wr + k);
    acc += xv[0] * (float)wv[0];
    acc += xv[1] * (float)wv[1];
    acc += xv[2] * (float)wv[2];
    acc += xv[3] * (float)wv[3];
  }
  out[idx] = acc * scale[n] + bias[n];
}

// ---------------- launch ----------------

extern "C" void kernel_launch(void* const* d_in, const int* in_sizes, int n_in,
                              void* d_out, int out_size, void* d_ws, size_t ws_size,
                              hipStream_t stream) {
  const float* x = (const float*)d_in[0];
  const int* wq = (const int*)d_in[1];
  const float* scale = (const float*)d_in[2];
  const float* bias = (const float*)d_in[3];
  float* out = (float*)d_out;

  const size_t xq_bytes = (size_t)M_DIM * K_DIM;         // 8.4 MB
  const size_t xs_bytes = (size_t)M_DIM * sizeof(float); // 8 KB
  const size_t wq_bytes = (size_t)N_DIM * K_DIM;         // 45.1 MB

  if (ws_size >= xq_bytes + xs_bytes + wq_bytes) {
    signed char* xq = (signed char*)d_ws;
    float* xs = (float*)((char*)d_ws + xq_bytes);
    signed char* wq8 = (signed char*)((char*)d_ws + xq_bytes + xs_bytes);

    const int prep_grid = M_DIM + NW16 / 256;  // 2048 + 11008 = 13056
    prep_kernel<<<prep_grid, 256, 0, stream>>>(x, xq, xs, wq, (i4*)wq8);

    gemm_i8<<<GRID, 256, 0, stream>>>(xq, wq8, xs, scale, bias, out);
  } else {
    const size_t total = (size_t)M_DIM * N_DIM;
    naive_kernel<<<(unsigned)((total + 255) / 256), 256, 0, stream>>>(x, wq, scale, bias, out);
  }
}